// Round 15
// baseline (989.970 us; speedup 1.0000x reference)
//
#include <hip/hip_runtime.h>
#include <math.h>

// ---------------------------------------------------------------------------
// Disentangler: 32 component-MLPs over sampled token rows + masked seg-pool.
// Round-15: ALGEBRAIC RESTRUCTURE. The masked segment-sum commutes with the
// (linear) second layer: pooled[t] = (sum_{unique r, seg=t} h(r)) @ W2 + n_t*b2.
// gemm1 (r12's proven 256x128/dbuf-A/fused-W1-transpose loop) now seg-reduces
// gelu outputs in its epilogue -> partial[comp][mt][16][2048]; h is never
// materialized. gemm3 (tiny, BW-bound: one fp32 read of W2) computes
// hsum @ W2 + n_t*b2 and writes out with the /4096 scale. gemm2 + reduce
// kernels deleted (~280 us and 137 GFLOP removed).
// ---------------------------------------------------------------------------

typedef __attribute__((ext_vector_type(8))) short bf16x8;
typedef __attribute__((ext_vector_type(4))) float f32x4;
typedef unsigned int u32;

constexpr int TT    = 16;
constexpr int TOKN  = 4096;
constexpr int DD    = 2048;
constexpr int HH    = 2048;
constexpr int CC    = 1024;
constexpr int LL    = 1000;
constexpr int NCOMP = 32;
constexpr int MP    = 1024;
constexpr int BMX = 256, BNX = 128;
constexpr int MTX  = MP / BMX;    // 4 m-tiles
constexpr int NT1 = HH / BNX;     // 16 n-tiles (gemm1)
constexpr int NT  = DD / 64;      // 32 K-tiles

__device__ __forceinline__ short f2bf(float f) {
  __bf16 h = (__bf16)f;
  return *reinterpret_cast<short*>(&h);
}
// Row swizzle (period 64): data-granule g of a 64-elem chunk lives at slot
// g ^ swz(row). Identical layout in Ab and the LDS tiles.
__device__ __forceinline__ int swz(int row) {
  return (row & 7) ^ ((row >> 3) & 7);
}
__device__ __forceinline__ int sw(int row, int gran) {   // short offset
  return (row << 6) + ((gran ^ swz(row)) << 3);
}
__device__ __forceinline__ void gl_lds16(const void* g, void* l) {
  __builtin_amdgcn_global_load_lds(
      (const __attribute__((address_space(1))) u32*)g,
      (__attribute__((address_space(3))) u32*)l, 16, 0, 0);
}

// --------------------------- dedup + per-t unique counts -------------------
__global__ void dedup_kernel(const int* __restrict__ ridx,
                             unsigned* __restrict__ bitmap,
                             float* __restrict__ keepf,
                             int* __restrict__ counts) {
  __shared__ int cnt[TT];
  int comp = blockIdx.x;
  if (threadIdx.x < TT) cnt[threadIdx.x] = 0;
  __syncthreads();
  for (int l = threadIdx.x; l < MP; l += 256) {
    float kv = 0.0f;
    if (l < LL) {
      int r = ridx[comp * LL + l];
      unsigned bit = 1u << (r & 31);
      unsigned old = atomicOr(&bitmap[(comp << 10) + (r >> 5)], bit);
      if (!(old & bit)) { kv = 1.0f; atomicAdd(&cnt[r >> 11], 1); }
    }
    keepf[(comp << 10) + l] = kv;
  }
  __syncthreads();
  if (threadIdx.x < TT) counts[comp * TT + threadIdx.x] = cnt[threadIdx.x];
}

// --------------------------- gather: x rows -> pre-swizzled bf16 -----------
__global__ __launch_bounds__(256) void gather_kernel(
    const float* __restrict__ x, const int* __restrict__ ridx,
    short* __restrict__ Ab) {
  int bid = blockIdx.x;
  int comp = bid >> 7, rgrp = bid & 127;
  int t = threadIdx.x;
  int tr = t >> 5, tn = t & 31;
  int m = rgrp * 8 + tr;
  int mi = m < LL ? m : LL - 1;
  int r = ridx[comp * LL + mi];
  int tokoff = comp >= 16 ? TOKN / 2 : 0;
  const float* src = x + ((size_t)(r >> 11) * TOKN + (r & 2047) + tokoff) * DD;
  short* drow = Ab + ((size_t)(comp * MP + m)) * DD;
  int s_m = swz(m);
#pragma unroll
  for (int i = 0; i < 8; ++i) {
    int gi = tn + 32 * i;
    float4 f0 = *reinterpret_cast<const float4*>(src + gi * 8);
    float4 f1 = *reinterpret_cast<const float4*>(src + gi * 8 + 4);
    bf16x8 pk;
    pk[0]=f2bf(f0.x); pk[1]=f2bf(f0.y); pk[2]=f2bf(f0.z); pk[3]=f2bf(f0.w);
    pk[4]=f2bf(f1.x); pk[5]=f2bf(f1.y); pk[6]=f2bf(f1.z); pk[7]=f2bf(f1.w);
    int c = gi >> 3, g = gi & 7;
    *reinterpret_cast<bf16x8*>(&drow[c * 64 + ((g ^ s_m) << 3)]) = pk;
  }
}

// --------------------------- K-loop (r12, unchanged) -----------------------
// LDS (shorts): Abuf[2][16384] @0 (256 rows x 64k), Bbuf[8192] @32768.
// Steady-state tile t: gate vmcnt(16) (A(t) oldest beyond bB(t+1)+A(t+1)),
// compute, barrier, bwrite(t+1), bload(t+2), aglds(t+2), lgkm(0), barrier.
template<int LDW>
__device__ __forceinline__ void kloop(
    const short* __restrict__ aBase,   // bf16 pre-swizzled rows, stride 2048
    const float* __restrict__ wBase,   // fp32 W [k][LDW] at col offset nt*BNX
    short* sm, f32x4 (&acc)[8][4],
    int wm, int wn, int lr, int lg, int tid) {
  const short* aSrc0 = aBase + (size_t)(tid >> 3) * 2048 + (tid & 7) * 8;
  int ldsA0 = tid * 8;
  int tn = tid & 31, tkb = tid >> 5, bn0 = tn * 4;
  const float* wCol = wBase + bn0;

  float4 brB[8];

  auto aglds = [&](int t, int buf) {
    short* l = sm + buf * 16384;
#pragma unroll
    for (int q = 0; q < 8; ++q)
      gl_lds16(aSrc0 + (size_t)q * 65536 + t * 64, l + ldsA0 + q * 2048);
  };
  auto bload = [&](int t) {
    const float* bb = wCol + (size_t)(t * 64 + tkb * 8) * LDW;
#pragma unroll
    for (int i = 0; i < 8; ++i)
      brB[i] = *reinterpret_cast<const float4*>(bb + (size_t)i * LDW);
  };
  auto bwrite = [&]() {
    short* Bs = sm + 32768;
#pragma unroll
    for (int j = 0; j < 4; ++j) {
      bf16x8 pk;
#pragma unroll
      for (int i = 0; i < 8; ++i) pk[i] = f2bf((&brB[i].x)[j]);
      *reinterpret_cast<bf16x8*>(&Bs[sw(bn0 + j, tkb)]) = pk;
    }
  };
  auto compute = [&](int d) {
    const short* A = sm + d * 16384;
    const short* B = sm + 32768;
#pragma unroll
    for (int kk = 0; kk < 2; ++kk) {
      bf16x8 af[8], bfr[4];
#pragma unroll
      for (int i = 0; i < 8; ++i)
        af[i] = *reinterpret_cast<const bf16x8*>(&A[sw(wm + i * 16 + lr, kk * 4 + lg)]);
#pragma unroll
      for (int j = 0; j < 4; ++j)
        bfr[j] = *reinterpret_cast<const bf16x8*>(&B[sw(wn + j * 16 + lr, kk * 4 + lg)]);
      __builtin_amdgcn_s_setprio(1);
#pragma unroll
      for (int i = 0; i < 8; ++i)
#pragma unroll
        for (int j = 0; j < 4; ++j)
          acc[i][j] = __builtin_amdgcn_mfma_f32_16x16x32_bf16(af[i], bfr[j], acc[i][j], 0, 0, 0);
      __builtin_amdgcn_s_setprio(0);
    }
  };

  // prologue: bB(0) regs; A(0) glds; write B(0) (compiler waits bB(0) only,
  // vmcnt(8) -> A(0) stays in flight); bB(1); A(1) glds.
  bload(0);
  aglds(0, 0);
  bwrite();
  bload(1);
  aglds(1, 1);
  asm volatile("s_waitcnt lgkmcnt(0)" ::: "memory");
  __builtin_amdgcn_s_barrier();

#pragma unroll 1
  for (int t = 0; t < NT; ++t) {
    if (t < NT - 1) {
      asm volatile("s_waitcnt vmcnt(16)" ::: "memory");  // A(t) landed
    } else {
      asm volatile("s_waitcnt vmcnt(0)" ::: "memory");
    }
    __builtin_amdgcn_sched_barrier(0);
    compute(t & 1);
    __builtin_amdgcn_s_barrier();          // all waves done reading A(t), B(t)
    if (t + 1 < NT) {
      bwrite();                            // B(t+1) -> Bbuf (vmcnt(8) auto)
      if (t + 2 < NT) {
        bload(t + 2);                      // issued BEFORE aglds (ordering!)
        aglds(t + 2, t & 1);
      }
      asm volatile("s_waitcnt lgkmcnt(0)" ::: "memory");
      __builtin_amdgcn_s_barrier();
    }
  }
}

// ------------- GEMM1: seg-reduce( gelu(x_sel @ W1 + b1) ) ------------------
// Output: partial[comp][mt][16][2048] = per-m-tile, per-timestamp, keep-masked
// sums of gelu values. h never materializes.
__global__ __launch_bounds__(256, 2) void gemm1_kernel(
    const float* __restrict__ nW1, const float* __restrict__ nb1,
    const float* __restrict__ eW1, const float* __restrict__ eb1,
    const short* __restrict__ Ab, const int* __restrict__ ridx,
    const float* __restrict__ keepf, float* __restrict__ partial) {
  __shared__ short smem[40960];   // 80 KB

  constexpr int NWG = NCOMP * MTX * NT1;   // 2048
  constexpr int CPX = NWG / 8;
  int b0 = blockIdx.x;
  int lb = (b0 & 7) * CPX + (b0 >> 3);     // XCD-chunked (T1), bijective
  int comp = lb / (MTX * NT1);
  int rem  = lb % (MTX * NT1);
  int mt = rem / NT1, nt = rem % NT1;
  bool isEdge = comp >= 16;
  int k16 = isEdge ? comp - 16 : comp;
  const float* W1 = (isEdge ? eW1 : nW1) + (size_t)k16 * DD * HH;
  const float* b1 = (isEdge ? eb1 : nb1) + (size_t)k16 * HH;

  int tid = threadIdx.x, lane = tid & 63, wid = tid >> 6;
  int wm = (wid >> 1) << 7, wn = (wid & 1) << 6;   // 2x2 waves of 128x64
  int lr = lane & 15, lg = lane >> 4;

  f32x4 acc[8][4] = {};
  kloop<HH>(Ab + ((size_t)(comp * MP + mt * BMX)) * DD,
            W1 + nt * BNX, smem, acc, wm, wn, lr, lg, tid);

  // epilogue: +b1, exact gelu, keep-masked seg-reduce by timestamp.
  // part stride 257 (257%32==1): t spreads across banks.
  __builtin_amdgcn_s_barrier();
  float* part = (float*)smem;                     // 16*257 fp32 = 16448 B
  int*   tarr = (int*)((char*)smem + 16448);      // 256 ints
  float* karr = (float*)((char*)smem + 17472);    // 256 floats
  {
    int mglob = mt * BMX + tid;
    int mi = mglob < LL ? mglob : LL - 1;
    int r2 = ridx[comp * LL + mi];
    tarr[tid] = r2 >> 11;
    karr[tid] = keepf[(comp << 10) + mglob];      // 0 for padded/dup rows
  }
  for (int e = tid; e < TT * 257; e += 256) part[e] = 0.0f;
  __syncthreads();
  const float* b1p = b1 + nt * BNX;
#pragma unroll
  for (int i = 0; i < 8; ++i)
#pragma unroll
    for (int j = 0; j < 4; ++j) {
      int nl = wn + j * 16 + lr;
      float bias = b1p[nl];
#pragma unroll
      for (int rr = 0; rr < 4; ++rr) {
        int ml = wm + i * 16 + lg * 4 + rr;
        float v = acc[i][j][rr] + bias;
        float ge = 0.5f * v * (1.0f + erff(v * 0.70710678118654752f));
        atomicAdd(&part[tarr[ml] * 257 + nl], ge * karr[ml]);
      }
    }
  __syncthreads();
  float* pout = partial + ((size_t)(comp * MTX + mt) * TT) * HH + nt * BNX;
  for (int e = tid; e < TT * BNX; e += 256) {
    int t2 = e >> 7, c = e & 127;
    pout[(size_t)t2 * HH + c] = part[t2 * 257 + c];
  }
}

// ------------- GEMM3: out = (hsum @ W2 + n_t*b2) / 4096 --------------------
// hsum[comp][t][k] = sum over mt of partial; M=16 per comp -> BW-bound on the
// single fp32 read of W2. Block: (comp, 128-col chunk); 256 thr; tg=tid>>7
// handles 8 timestamps; per-kb staging of hsum[16][256] fp32 in LDS.
__global__ __launch_bounds__(256) void gemm3_kernel(
    const float* __restrict__ partial, const int* __restrict__ counts,
    const float* __restrict__ nW2, const float* __restrict__ nb2,
    const float* __restrict__ eW2, const float* __restrict__ eb2,
    float* __restrict__ out) {
  __shared__ float hs[TT * 256];   // 16 KB
  int bid = blockIdx.x;
  int comp = bid >> 3, chunk = bid & 7;
  bool isEdge = comp >= 16;
  int k16 = isEdge ? comp - 16 : comp;
  const float* W2 = (isEdge ? eW2 : nW2) + (size_t)k16 * HH * CC;
  const float* b2 = (isEdge ? eb2 : nb2) + (size_t)k16 * CC;
  int tid = threadIdx.x;
  int col = chunk * 128 + (tid & 127);
  int tg = tid >> 7;                         // 0/1 -> t in [tg*8, tg*8+8)
  float acc[8] = {};
  const float* pbase = partial + (size_t)comp * MTX * TT * HH;

  for (int kb = 0; kb < HH / 256; ++kb) {
    __syncthreads();
    for (int q = 0; q < 16; ++q) {
      int idx = q * 256 + tid;               // 0..4095
      int t = idx >> 8, k = idx & 255;
      float s = 0.0f;
#pragma unroll
      for (int mt = 0; mt < MTX; ++mt)
        s += pbase[((size_t)(mt * TT + t)) * HH + kb * 256 + k];
      hs[t * 256 + k] = s;
    }
    __syncthreads();
#pragma unroll 4
    for (int k = 0; k < 256; ++k) {
      float w = W2[(size_t)(kb * 256 + k) * CC + col];
#pragma unroll
      for (int tt = 0; tt < 8; ++tt)
        acc[tt] += hs[(tg * 8 + tt) * 256 + k] * w;
    }
  }
#pragma unroll
  for (int tt = 0; tt < 8; ++tt) {
    int t = tg * 8 + tt;
    float v = (acc[tt] + (float)counts[comp * TT + t] * b2[col]) * (1.0f / 4096.0f);
    out[(size_t)t * 32768 + comp * 1024 + col] = v;
  }
}

// ---------------------------------------------------------------------------
extern "C" void kernel_launch(void* const* d_in, const int* in_sizes, int n_in,
                              void* d_out, int out_size, void* d_ws, size_t ws_size,
                              hipStream_t stream) {
  const float* x    = (const float*)d_in[0];
  const int*   ridx = (const int*)d_in[3];
  const float* nW1  = (const float*)d_in[4];
  const float* nb1  = (const float*)d_in[5];
  const float* nW2  = (const float*)d_in[6];
  const float* nb2  = (const float*)d_in[7];
  const float* eW1  = (const float*)d_in[8];
  const float* eb1  = (const float*)d_in[9];
  const float* eW2  = (const float*)d_in[10];
  const float* eb2  = (const float*)d_in[11];
  float* out = (float*)d_out;

  // ws: [bitmap 128KB][keep 128KB][counts 2KB][partial 16.8MB][Ab 134MB] ~151MB
  const size_t BMP_B = (size_t)NCOMP * 1024 * 4;
  const size_t KP_B  = (size_t)NCOMP * 1024 * 4;
  const size_t CNT_B = (size_t)NCOMP * TT * 4;
  const size_t PRT_B = (size_t)NCOMP * MTX * TT * HH * 4;

  char* ws = (char*)d_ws;
  unsigned* bitmap = (unsigned*)ws;
  float* keepf     = (float*)(ws + BMP_B);
  int* counts      = (int*)(ws + BMP_B + KP_B);
  float* partial   = (float*)(ws + BMP_B + KP_B + CNT_B);
  short* Ab        = (short*)(ws + BMP_B + KP_B + CNT_B + PRT_B);

  hipMemsetAsync(bitmap, 0, BMP_B, stream);
  dedup_kernel<<<NCOMP, 256, 0, stream>>>(ridx, bitmap, keepf, counts);
  gather_kernel<<<NCOMP * 128, 256, 0, stream>>>(x, ridx, Ab);
  gemm1_kernel<<<NCOMP * MTX * NT1, 256, 0, stream>>>(nW1, nb1, eW1, eb1, Ab, ridx, keepf, partial);
  gemm3_kernel<<<NCOMP * 8, 256, 0, stream>>>(partial, counts, nW2, nb2, eW2, eb2, out);
}